// Round 1
// baseline (2207.818 us; speedup 1.0000x reference)
//
#include <hip/hip_runtime.h>

#define SEQ 512
#define BATCH 2048
#define HID 50
#define NG 200          // 4*H
#define BB 8            // batch per block
#define NTHR 512        // 8 waves
#define S1 60           // u1/w1 row stride in floats: [x(4) | h1(50) | pad(6)]
#define Q1 14           // float4 quads used in L1 dot (56 floats, last 2 zero)
#define S2 100          // u2/w2 row stride: [relu(h1)(50) | h2(50)]
#define Q2 25

// LDS layout (float offsets)
#define OFF_W1 0
#define OFF_W2 (OFF_W1 + NG * S1)        // 12000
#define OFF_U1 (OFF_W2 + NG * S2)        // 32000
#define OFF_U2 (OFF_U1 + BB * S1)        // 32480
#define OFF_G  (OFF_U2 + BB * S2)        // 33280
#define OFF_B1 (OFF_G + BB * NG)         // 34880
#define OFF_B2 (OFF_B1 + NG)             // 35080
#define OFF_WFC (OFF_B2 + NG)            // 35280
#define OFF_FC (OFF_WFC + 56)            // 35336
#define LDS_FLOATS (OFF_FC + BB * 56)    // 35784 -> 143136 bytes

__device__ __forceinline__ float sigf(float x) {
    // 1/(1+e^-x); v_exp + v_rcp, ~2ulp — plenty for 7.5e-4 threshold
    return __builtin_amdgcn_rcpf(1.0f + __expf(-x));
}
__device__ __forceinline__ float tanhf_(float x) {
    // tanh(x) = 1 - 2/(1+e^{2x}); saturates correctly at +-inf
    return 1.0f - 2.0f * __builtin_amdgcn_rcpf(1.0f + __expf(2.0f * x));
}

__global__ __launch_bounds__(NTHR, 2) void lstm2_fused(
    const float* __restrict__ x,
    const float* __restrict__ w_ih1, const float* __restrict__ w_hh1,
    const float* __restrict__ b_ih1, const float* __restrict__ b_hh1,
    const float* __restrict__ w_ih2, const float* __restrict__ w_hh2,
    const float* __restrict__ b_ih2, const float* __restrict__ b_hh2,
    const float* __restrict__ w_fc, const float* __restrict__ b_fc,
    float* __restrict__ out)
{
    extern __shared__ float sm[];
    const int tid = threadIdx.x;
    const int bbase = blockIdx.x * BB;

    // gate-phase identity: wave covers 8 batch x 8 gate-row slots
    const int wv = tid >> 6;       // wave 0..7 -> rows [25w, 25w+25)
    const int lane = tid & 63;
    const int s = lane >> 3;       // gate slot 0..7
    const int b = lane & 7;        // batch 0..7
    const int r0 = 25 * wv;

    // update-phase identity (tid < 400): one (batch, hidden-unit) per thread
    const int ub = tid / HID;
    const int uj = tid - ub * HID;

    // ---------------- setup: stage weights into LDS ----------------
    for (int idx = tid; idx < NG * S1; idx += NTHR) {
        int r = idx / S1, k = idx - r * S1;
        float v = 0.0f;
        if (k < 4) v = w_ih1[r * 4 + k];
        else if (k < 4 + HID) v = w_hh1[r * HID + (k - 4)];
        sm[OFF_W1 + idx] = v;
    }
    for (int idx = tid; idx < NG * S2; idx += NTHR) {
        int r = idx / S2, k = idx - r * S2;
        sm[OFF_W2 + idx] = (k < HID) ? w_ih2[r * HID + k] : w_hh2[r * HID + (k - HID)];
    }
    if (tid < NG) {
        sm[OFF_B1 + tid] = b_ih1[tid] + b_hh1[tid];
        sm[OFF_B2 + tid] = b_ih2[tid] + b_hh2[tid];
    }
    for (int idx = tid; idx < 56; idx += NTHR) sm[OFF_WFC + idx] = (idx < HID) ? w_fc[idx] : 0.0f;
    for (int idx = tid; idx < BB * S1; idx += NTHR) sm[OFF_U1 + idx] = 0.0f;
    for (int idx = tid; idx < BB * S2; idx += NTHR) sm[OFF_U2 + idx] = 0.0f;
    for (int idx = tid; idx < BB * 56; idx += NTHR) sm[OFF_FC + idx] = 0.0f;
    __syncthreads();
    if (tid < BB) {
        // x(t=0) into u1 x-slot
        const float4 x0 = *reinterpret_cast<const float4*>(x + (size_t)(bbase + tid) * 4);
        *reinterpret_cast<float4*>(&sm[OFF_U1 + tid * S1]) = x0;
    }
    float c1 = 0.0f, c2 = 0.0f;
    const float bfc = b_fc[0];
    __syncthreads();

    const float4* w1q = reinterpret_cast<const float4*>(&sm[OFF_W1]);
    const float4* w2q = reinterpret_cast<const float4*>(&sm[OFF_W2]);
    const float4* u1q = reinterpret_cast<const float4*>(&sm[OFF_U1]);
    const float4* u2q = reinterpret_cast<const float4*>(&sm[OFF_U2]);

#pragma unroll 1
    for (int t = 0; t < SEQ; ++t) {
        // issue x(t+1) prefetch early (lanes 448..455), lands before bar A consumer
        float4 xr = make_float4(0.f, 0.f, 0.f, 0.f);
        if (tid >= 448 && tid < 448 + BB) {
            int tn = (t + 1 < SEQ) ? t + 1 : SEQ - 1;
            xr = *reinterpret_cast<const float4*>(
                x + ((size_t)tn * BATCH + bbase + (tid - 448)) * 4);
        }

        // ---------------- L1 gate phase ----------------
        float4 U1[Q1];
#pragma unroll
        for (int q = 0; q < Q1; ++q) U1[q] = u1q[b * (S1 / 4) + q];
#pragma unroll
        for (int p = 0; p < 3; ++p) {
            int r = r0 + 8 * p + s;               // consecutive rows across slots
            float a0 = sm[OFF_B1 + r], a1 = 0.f, a2 = 0.f, a3 = 0.f;
#pragma unroll
            for (int q = 0; q < Q1; ++q) {
                float4 wq = w1q[r * (S1 / 4) + q];
                a0 += wq.x * U1[q].x; a1 += wq.y * U1[q].y;
                a2 += wq.z * U1[q].z; a3 += wq.w * U1[q].w;
            }
            sm[OFF_G + b * NG + r] = (a0 + a1) + (a2 + a3);
        }
        {   // remainder row r0+24: k-split across slots + shuffle reduce
            int r = r0 + 24;
            float4 wq = w1q[r * (S1 / 4) + s];
            float4 uq = u1q[b * (S1 / 4) + s];
            float a = wq.x * uq.x + wq.y * uq.y + wq.z * uq.z + wq.w * uq.w;
            if (s < Q1 - 8) {
                float4 wq2 = w1q[r * (S1 / 4) + s + 8];
                float4 uq2 = u1q[b * (S1 / 4) + s + 8];
                a += wq2.x * uq2.x + wq2.y * uq2.y + wq2.z * uq2.z + wq2.w * uq2.w;
            }
            a += __shfl_xor(a, 8); a += __shfl_xor(a, 16); a += __shfl_xor(a, 32);
            if (s == 0) sm[OFF_G + b * NG + r] = a + sm[OFF_B1 + r];
        }
        __syncthreads();  // bar A

        // ---------------- L1 update ----------------
        if (tid < BB * HID) {
            float gi = sm[OFF_G + ub * NG + uj];
            float gf = sm[OFF_G + ub * NG + HID + uj];
            float gg = sm[OFF_G + ub * NG + 2 * HID + uj];
            float go = sm[OFF_G + ub * NG + 3 * HID + uj];
            float ig = sigf(gi), fg = sigf(gf), cg = tanhf_(gg), og = sigf(go);
            c1 = fg * c1 + ig * cg;
            float h1 = og * tanhf_(c1);
            sm[OFF_U1 + ub * S1 + 4 + uj] = h1;              // next step's recurrent input
            sm[OFF_U2 + ub * S2 + uj] = fmaxf(h1, 0.0f);     // L2 input (relu)
        } else if (tid >= 448 && tid < 448 + BB) {
            *reinterpret_cast<float4*>(&sm[OFF_U1 + (tid - 448) * S1]) = xr;  // x(t+1)
        }
        __syncthreads();  // bar B

        // ---------------- L2 gate phase ----------------
        float4 U2[Q2];
#pragma unroll
        for (int q = 0; q < Q2; ++q) U2[q] = u2q[b * (S2 / 4) + q];
#pragma unroll
        for (int p = 0; p < 3; ++p) {
            int r = r0 + 8 * p + s;
            float a0 = sm[OFF_B2 + r], a1 = 0.f, a2 = 0.f, a3 = 0.f;
#pragma unroll
            for (int q = 0; q < Q2; ++q) {
                float4 wq = w2q[r * (S2 / 4) + q];
                a0 += wq.x * U2[q].x; a1 += wq.y * U2[q].y;
                a2 += wq.z * U2[q].z; a3 += wq.w * U2[q].w;
            }
            sm[OFF_G + b * NG + r] = (a0 + a1) + (a2 + a3);
        }
        {   // remainder row
            int r = r0 + 24;
            float a = 0.0f;
#pragma unroll
            for (int m = 0; m < 4; ++m) {
                int q = s + 8 * m;
                if (q < Q2) {
                    float4 wq = w2q[r * (S2 / 4) + q];
                    float4 uq = u2q[b * (S2 / 4) + q];
                    a += wq.x * uq.x + wq.y * uq.y + wq.z * uq.z + wq.w * uq.w;
                }
            }
            a += __shfl_xor(a, 8); a += __shfl_xor(a, 16); a += __shfl_xor(a, 32);
            if (s == 0) sm[OFF_G + b * NG + r] = a + sm[OFF_B2 + r];
        }
        __syncthreads();  // bar C

        // ---------------- L2 update + fc partials ----------------
        if (tid < BB * HID) {
            float gi = sm[OFF_G + ub * NG + uj];
            float gf = sm[OFF_G + ub * NG + HID + uj];
            float gg = sm[OFF_G + ub * NG + 2 * HID + uj];
            float go = sm[OFF_G + ub * NG + 3 * HID + uj];
            float ig = sigf(gi), fg = sigf(gf), cg = tanhf_(gg), og = sigf(go);
            c2 = fg * c2 + ig * cg;
            float h2 = og * tanhf_(c2);
            sm[OFF_U2 + ub * S2 + HID + uj] = h2;            // next step's recurrent input
            sm[OFF_FC + ub * 56 + uj] = fmaxf(h2, 0.0f) * sm[OFF_WFC + uj];
        }
        __syncthreads();  // bar D

        // ---------------- fc reduce: 8 outputs (wave 0 only; others run ahead) ----
        if (tid < 64) {
            int rb = tid >> 3, m = tid & 7;
            float v = 0.0f;
#pragma unroll
            for (int k2 = 0; k2 < 7; ++k2) v += sm[OFF_FC + rb * 56 + m + 8 * k2];
            v += __shfl_xor(v, 1); v += __shfl_xor(v, 2); v += __shfl_xor(v, 4);
            if (m == 0) out[(size_t)t * BATCH + bbase + rb] = v + bfc;
        }
        // no barrier needed: fc reads OFF_FC which is next written only after bar C
        // of the next iteration; gate buffer writers don't touch OFF_FC.
    }
}

extern "C" void kernel_launch(void* const* d_in, const int* in_sizes, int n_in,
                              void* d_out, int out_size, void* d_ws, size_t ws_size,
                              hipStream_t stream) {
    const float* X     = (const float*)d_in[0];
    const float* Wih1  = (const float*)d_in[1];
    const float* Whh1  = (const float*)d_in[2];
    const float* Bih1  = (const float*)d_in[3];
    const float* Bhh1  = (const float*)d_in[4];
    const float* Wih2  = (const float*)d_in[5];
    const float* Whh2  = (const float*)d_in[6];
    const float* Bih2  = (const float*)d_in[7];
    const float* Bhh2  = (const float*)d_in[8];
    const float* Wfc   = (const float*)d_in[9];
    const float* Bfc   = (const float*)d_in[10];
    float* out = (float*)d_out;

    const size_t shbytes = (size_t)LDS_FLOATS * sizeof(float);
    // >64KB dynamic LDS needs the attribute; host-side config, capture-safe.
    (void)hipFuncSetAttribute((const void*)lstm2_fused,
                              hipFuncAttributeMaxDynamicSharedMemorySize,
                              (int)shbytes);

    lstm2_fused<<<dim3(BATCH / BB), dim3(NTHR), shbytes, stream>>>(
        X, Wih1, Whh1, Bih1, Bhh1, Wih2, Whh2, Bih2, Bhh2, Wfc, Bfc, out);
}

// Round 2
// 1704.643 us; speedup vs baseline: 1.2952x; 1.2952x over previous
//
#include <hip/hip_runtime.h>
#include <cstdint>

#define SEQ 512
#define BATCH 2048
#define HID 50
#define NG 200          // 4*H
#define BB 8            // batch per block
#define NTHR 512        // 8 waves
#define S1H 72          // u1/w1 row stride in HALVES: [x(4)|h1(50)|pad..72], 144 B (16B-aligned)
#define Q1 7            // uint4 (8-half) quads per L1 row (56 halves; 54 used)
#define S2H 104         // [relu(h1)(50)|h2(50)|pad(4)], 208 B
#define Q2 13

typedef _Float16 f16;
typedef _Float16 f16x2 __attribute__((ext_vector_type(2)));

// ---- dynamic-LDS byte offsets (all fp16 regions 16B-aligned) ----
#define OFFB_W1 0
#define OFFB_W2 (OFFB_W1 + NG * S1H * 2)        // 28800
#define OFFB_U1 (OFFB_W2 + NG * S2H * 2)        // 70400
#define OFFB_U2 (OFFB_U1 + BB * S1H * 2)        // 71552
#define OFFB_G  (OFFB_U2 + BB * S2H * 2)        // 73216 (fp32 gates)
#define OFFB_B1 (OFFB_G + BB * NG * 4)          // 79616
#define OFFB_B2 (OFFB_B1 + NG * 4)              // 80416
#define OFFB_WFC (OFFB_B2 + NG * 4)             // 81216
#define OFFB_FC (OFFB_WFC + 56 * 4)             // 81440
#define LDS_BYTES (OFFB_FC + BB * 56 * 4)       // 83232

__device__ __forceinline__ float dot2acc(unsigned w, unsigned u, float acc) {
#if __has_builtin(__builtin_amdgcn_fdot2)
    return __builtin_amdgcn_fdot2(__builtin_bit_cast(f16x2, w),
                                  __builtin_bit_cast(f16x2, u), acc, false);
#else
    f16x2 a = __builtin_bit_cast(f16x2, w), b = __builtin_bit_cast(f16x2, u);
    acc = fmaf((float)a.x, (float)b.x, acc);
    return fmaf((float)a.y, (float)b.y, acc);
#endif
}
__device__ __forceinline__ float dotq(uint4 w, uint4 u, float acc) {
    acc = dot2acc(w.x, u.x, acc);
    acc = dot2acc(w.y, u.y, acc);
    acc = dot2acc(w.z, u.z, acc);
    return dot2acc(w.w, u.w, acc);
}

// exact IEEE divide (compiler div sequence) — buys precision headroom for fp16 weights
__device__ __forceinline__ float sigf(float x)   { return 1.0f / (1.0f + __expf(-x)); }
__device__ __forceinline__ float tanhf_(float x) { return 1.0f - 2.0f / (1.0f + __expf(2.0f * x)); }

__global__ __launch_bounds__(NTHR, 2) void lstm2_fused(
    const float* __restrict__ x,
    const float* __restrict__ w_ih1, const float* __restrict__ w_hh1,
    const float* __restrict__ b_ih1, const float* __restrict__ b_hh1,
    const float* __restrict__ w_ih2, const float* __restrict__ w_hh2,
    const float* __restrict__ b_ih2, const float* __restrict__ b_hh2,
    const float* __restrict__ w_fc, const float* __restrict__ b_fc,
    float* __restrict__ out)
{
    extern __shared__ char smraw[];
    f16*   w1h = (f16*)(smraw + OFFB_W1);
    f16*   w2h = (f16*)(smraw + OFFB_W2);
    f16*   u1h = (f16*)(smraw + OFFB_U1);
    f16*   u2h = (f16*)(smraw + OFFB_U2);
    float* Gf  = (float*)(smraw + OFFB_G);
    float* B1f = (float*)(smraw + OFFB_B1);
    float* B2f = (float*)(smraw + OFFB_B2);
    float* wfc = (float*)(smraw + OFFB_WFC);
    float* fcb = (float*)(smraw + OFFB_FC);

    const uint4* w1q = (const uint4*)(smraw + OFFB_W1);   // row stride 9 uint4
    const uint4* w2q = (const uint4*)(smraw + OFFB_W2);   // row stride 13 uint4
    const uint4* u1q = (const uint4*)(smraw + OFFB_U1);
    const uint4* u2q = (const uint4*)(smraw + OFFB_U2);

    const int tid = threadIdx.x;
    const int bbase = blockIdx.x * BB;

    // gate-phase identity: wave covers 8 gate-row slots x 8 batches
    const int wv = tid >> 6;
    const int lane = tid & 63;
    const int s = lane >> 3;       // slot 0..7
    const int b = lane & 7;        // batch 0..7
    const int r0 = 25 * wv;

    // update-phase identity (tid < 400)
    const int ub = tid / HID;
    const int uj = tid - ub * HID;

    // ---------------- stage weights (fp32 -> fp16) ----------------
    for (int idx = tid; idx < NG * S1H; idx += NTHR) {
        int r = idx / S1H, k = idx - r * S1H;
        float v = 0.0f;
        if (k < 4) v = w_ih1[r * 4 + k];
        else if (k < 4 + HID) v = w_hh1[r * HID + (k - 4)];
        w1h[idx] = (f16)v;
    }
    for (int idx = tid; idx < NG * S2H; idx += NTHR) {
        int r = idx / S2H, k = idx - r * S2H;
        float v = 0.0f;
        if (k < HID) v = w_ih2[r * HID + k];
        else if (k < 2 * HID) v = w_hh2[r * HID + (k - HID)];
        w2h[idx] = (f16)v;
    }
    if (tid < NG) {
        B1f[tid] = b_ih1[tid] + b_hh1[tid];
        B2f[tid] = b_ih2[tid] + b_hh2[tid];
    }
    for (int idx = tid; idx < 56; idx += NTHR) wfc[idx] = (idx < HID) ? w_fc[idx] : 0.0f;
    for (int idx = tid; idx < BB * S1H; idx += NTHR) u1h[idx] = (f16)0.0f;
    for (int idx = tid; idx < BB * S2H; idx += NTHR) u2h[idx] = (f16)0.0f;
    for (int idx = tid; idx < BB * 56; idx += NTHR) fcb[idx] = 0.0f;
    __syncthreads();
    if (tid < BB) {
        const float4 x0 = *reinterpret_cast<const float4*>(x + (size_t)(bbase + tid) * 4);
        f16x2 p0 = {(f16)x0.x, (f16)x0.y}, p1 = {(f16)x0.z, (f16)x0.w};
        uint2 pk;
        pk.x = __builtin_bit_cast(unsigned, p0);
        pk.y = __builtin_bit_cast(unsigned, p1);
        *reinterpret_cast<uint2*>(u1h + tid * S1H) = pk;
    }
    float c1 = 0.0f, c2 = 0.0f;
    const float bfc = b_fc[0];
    __syncthreads();

#pragma unroll 1
    for (int t = 0; t < SEQ; ++t) {
        // x(t+1) prefetch (lanes 448..455)
        float4 xr = make_float4(0.f, 0.f, 0.f, 0.f);
        if (tid >= 448 && tid < 448 + BB) {
            int tn = (t + 1 < SEQ) ? t + 1 : SEQ - 1;
            xr = *reinterpret_cast<const float4*>(
                x + ((size_t)tn * BATCH + bbase + (tid - 448)) * 4);
        }

        // ---------------- L1 gates ----------------
        uint4 U1r[Q1];
#pragma unroll
        for (int q = 0; q < Q1; ++q) U1r[q] = u1q[b * 9 + q];
#pragma unroll
        for (int p = 0; p < 3; ++p) {
            int r = r0 + 8 * p + s;
            float acc = B1f[r];
#pragma unroll
            for (int q = 0; q < Q1; ++q) acc = dotq(w1q[r * 9 + q], U1r[q], acc);
            Gf[b * NG + r] = acc;
        }
        {   // remainder row r0+24: k-split across slots (s==7 reads zero pad quad)
            int r = r0 + 24;
            float a = dotq(w1q[r * 9 + s], u1q[b * 9 + s], 0.0f);
            a += __shfl_xor(a, 8); a += __shfl_xor(a, 16); a += __shfl_xor(a, 32);
            if (s == 0) Gf[b * NG + r] = a + B1f[r];
        }
        __syncthreads();  // bar A

        // ---------------- L1 update ----------------
        if (tid < BB * HID) {
            float gi = Gf[ub * NG + uj];
            float gf = Gf[ub * NG + HID + uj];
            float gg = Gf[ub * NG + 2 * HID + uj];
            float go = Gf[ub * NG + 3 * HID + uj];
            float ig = sigf(gi), fg = sigf(gf), cg = tanhf_(gg), og = sigf(go);
            c1 = fg * c1 + ig * cg;
            float h1 = og * tanhf_(c1);
            u1h[ub * S1H + 4 + uj] = (f16)h1;
            u2h[ub * S2H + uj] = (f16)fmaxf(h1, 0.0f);
        } else if (tid >= 448 && tid < 448 + BB) {
            f16x2 p0 = {(f16)xr.x, (f16)xr.y}, p1 = {(f16)xr.z, (f16)xr.w};
            uint2 pk;
            pk.x = __builtin_bit_cast(unsigned, p0);
            pk.y = __builtin_bit_cast(unsigned, p1);
            *reinterpret_cast<uint2*>(u1h + (tid - 448) * S1H) = pk;
        }
        __syncthreads();  // bar B

        // ---------------- L2 gates ----------------
        uint4 U2r[Q2];
#pragma unroll
        for (int q = 0; q < Q2; ++q) U2r[q] = u2q[b * 13 + q];
#pragma unroll
        for (int p = 0; p < 3; ++p) {
            int r = r0 + 8 * p + s;
            float acc = B2f[r];
#pragma unroll
            for (int q = 0; q < Q2; ++q) acc = dotq(w2q[r * 13 + q], U2r[q], acc);
            Gf[b * NG + r] = acc;
        }
        {   // remainder row: quads s and s+8 (s<5)
            int r = r0 + 24;
            float a = dotq(w2q[r * 13 + s], u2q[b * 13 + s], 0.0f);
            if (s < 5) a = dotq(w2q[r * 13 + s + 8], u2q[b * 13 + s + 8], a);
            a += __shfl_xor(a, 8); a += __shfl_xor(a, 16); a += __shfl_xor(a, 32);
            if (s == 0) Gf[b * NG + r] = a + B2f[r];
        }
        __syncthreads();  // bar C

        // ---------------- L2 update + fc partials ----------------
        if (tid < BB * HID) {
            float gi = Gf[ub * NG + uj];
            float gf = Gf[ub * NG + HID + uj];
            float gg = Gf[ub * NG + 2 * HID + uj];
            float go = Gf[ub * NG + 3 * HID + uj];
            float ig = sigf(gi), fg = sigf(gf), cg = tanhf_(gg), og = sigf(go);
            c2 = fg * c2 + ig * cg;
            float h2 = og * tanhf_(c2);
            u2h[ub * S2H + HID + uj] = (f16)h2;               // recurrent path (fp16)
            fcb[ub * 56 + uj] = fmaxf(h2, 0.0f) * wfc[uj];    // output path (fp32 h2)
        }
        __syncthreads();  // bar D

        // ---------------- fc reduce (wave 0) ----------------
        if (tid < 64) {
            int rb = tid >> 3, m = tid & 7;
            float v = 0.0f;
#pragma unroll
            for (int k2 = 0; k2 < 7; ++k2) v += fcb[rb * 56 + m + 8 * k2];
            v += __shfl_xor(v, 1); v += __shfl_xor(v, 2); v += __shfl_xor(v, 4);
            if (m == 0) out[(size_t)t * BATCH + bbase + rb] = v + bfc;
        }
        // fcb next written only after bar C of the next iteration — safe without a barrier
    }
}

extern "C" void kernel_launch(void* const* d_in, const int* in_sizes, int n_in,
                              void* d_out, int out_size, void* d_ws, size_t ws_size,
                              hipStream_t stream) {
    const float* X    = (const float*)d_in[0];
    const float* Wih1 = (const float*)d_in[1];
    const float* Whh1 = (const float*)d_in[2];
    const float* Bih1 = (const float*)d_in[3];
    const float* Bhh1 = (const float*)d_in[4];
    const float* Wih2 = (const float*)d_in[5];
    const float* Whh2 = (const float*)d_in[6];
    const float* Bih2 = (const float*)d_in[7];
    const float* Bhh2 = (const float*)d_in[8];
    const float* Wfc  = (const float*)d_in[9];
    const float* Bfc  = (const float*)d_in[10];
    float* out = (float*)d_out;

    (void)hipFuncSetAttribute((const void*)lstm2_fused,
                              hipFuncAttributeMaxDynamicSharedMemorySize,
                              (int)LDS_BYTES);

    lstm2_fused<<<dim3(BATCH / BB), dim3(NTHR), LDS_BYTES, stream>>>(
        X, Wih1, Whh1, Bih1, Bhh1, Wih2, Whh2, Bih2, Bhh2, Wfc, Bfc, out);
}

// Round 3
// 1547.922 us; speedup vs baseline: 1.4263x; 1.1012x over previous
//
#include <hip/hip_runtime.h>
#include <cstdint>

#define SEQ 512
#define BATCH 2048
#define HID 50
#define NG 200          // 4*H
#define BB 4            // batch per block
#define NTHR 512        // 8 waves
#define NBLK (BATCH / BB)  // 512 blocks -> 2 blocks/CU
#define S1H 56          // u1/w1 row stride in halves: [x(4)|h1(50)|pad(2)], 112 B
#define Q1 7            // uint4 (8-half) quads per L1 row
#define S2H 104         // [relu(h1)(50)|h2(50)|pad(4)], 208 B
#define Q2 13

typedef _Float16 f16;
typedef _Float16 f16x2 __attribute__((ext_vector_type(2)));

// ---- dynamic-LDS byte offsets (16B-aligned) ----
#define OFFB_W1 0
#define OFFB_W2 (OFFB_W1 + NG * S1H * 2)   // 22400
#define OFFB_U1 (OFFB_W2 + NG * S2H * 2)   // 64000
#define OFFB_U2 (OFFB_U1 + BB * S1H * 2)   // 64448
#define OFFB_G1 (OFFB_U2 + BB * S2H * 2)   // 65280
#define OFFB_G2 (OFFB_G1 + BB * NG * 4)    // 68480
#define OFFB_B1 (OFFB_G2 + BB * NG * 4)    // 71680
#define OFFB_B2 (OFFB_B1 + NG * 4)         // 72480
#define LDS_BYTES (OFFB_B2 + NG * 4)       // 73280 -> 2 blocks/CU fits 160 KiB

__device__ __forceinline__ float dot2acc(unsigned w, unsigned u, float acc) {
#if __has_builtin(__builtin_amdgcn_fdot2)
    return __builtin_amdgcn_fdot2(__builtin_bit_cast(f16x2, w),
                                  __builtin_bit_cast(f16x2, u), acc, false);
#else
    f16x2 a = __builtin_bit_cast(f16x2, w), b = __builtin_bit_cast(f16x2, u);
    acc = fmaf((float)a.x, (float)b.x, acc);
    return fmaf((float)a.y, (float)b.y, acc);
#endif
}
__device__ __forceinline__ float dotq(uint4 w, uint4 u, float acc) {
    acc = dot2acc(w.x, u.x, acc);
    acc = dot2acc(w.y, u.y, acc);
    acc = dot2acc(w.z, u.z, acc);
    return dot2acc(w.w, u.w, acc);
}

// rcp-based activations: short dependent chain; validated 2.4e-4 absmax in R1
__device__ __forceinline__ float sigf(float x) {
    return __builtin_amdgcn_rcpf(1.0f + __expf(-x));
}
__device__ __forceinline__ float tanhf_(float x) {
    return 1.0f - 2.0f * __builtin_amdgcn_rcpf(1.0f + __expf(2.0f * x));
}

__global__ __launch_bounds__(NTHR, 4) void lstm2_fused(
    const float* __restrict__ x,
    const float* __restrict__ w_ih1, const float* __restrict__ w_hh1,
    const float* __restrict__ b_ih1, const float* __restrict__ b_hh1,
    const float* __restrict__ w_ih2, const float* __restrict__ w_hh2,
    const float* __restrict__ b_ih2, const float* __restrict__ b_hh2,
    const float* __restrict__ w_fc, const float* __restrict__ b_fc,
    float* __restrict__ out)
{
    extern __shared__ char smraw[];
    f16*   w1h = (f16*)(smraw + OFFB_W1);
    f16*   w2h = (f16*)(smraw + OFFB_W2);
    f16*   u1h = (f16*)(smraw + OFFB_U1);
    f16*   u2h = (f16*)(smraw + OFFB_U2);
    float* G1f = (float*)(smraw + OFFB_G1);
    float* G2f = (float*)(smraw + OFFB_G2);
    float* B1f = (float*)(smraw + OFFB_B1);
    float* B2f = (float*)(smraw + OFFB_B2);

    const uint4* w1q = (const uint4*)(smraw + OFFB_W1);   // row stride Q1 uint4
    const uint4* w2q = (const uint4*)(smraw + OFFB_W2);   // row stride Q2 uint4
    const uint4* u1q = (const uint4*)(smraw + OFFB_U1);
    const uint4* u2q = (const uint4*)(smraw + OFFB_U2);

    const int tid  = threadIdx.x;
    const int wv   = tid >> 6;
    const int lane = tid & 63;
    const int bbase = blockIdx.x * BB;

    // gate-phase identity: 4 batches x 16 row-slots per wave; wave owns 25 rows
    const int b  = lane & 3;
    const int s  = lane >> 2;      // 0..15
    const int r0 = 25 * wv;

    // update-phase identity: wave = batch (waves 0-3: L1, waves 4-7: L2)
    const int ubat = (wv < 4) ? wv : (wv - 4);

    // ---------------- stage weights (fp32 -> fp16) ----------------
    for (int idx = tid; idx < NG * S1H; idx += NTHR) {
        int r = idx / S1H, k = idx - r * S1H;
        float v = 0.0f;
        if (k < 4) v = w_ih1[r * 4 + k];
        else if (k < 4 + HID) v = w_hh1[r * HID + (k - 4)];
        w1h[idx] = (f16)v;
    }
    for (int idx = tid; idx < NG * S2H; idx += NTHR) {
        int r = idx / S2H, k = idx - r * S2H;
        float v = 0.0f;
        if (k < HID) v = w_ih2[r * HID + k];
        else if (k < 2 * HID) v = w_hh2[r * HID + (k - HID)];
        w2h[idx] = (f16)v;
    }
    if (tid < NG) {
        B1f[tid] = b_ih1[tid] + b_hh1[tid];
        B2f[tid] = b_ih2[tid] + b_hh2[tid];
    }
    for (int idx = tid; idx < BB * S1H; idx += NTHR) u1h[idx] = (f16)0.0f;
    for (int idx = tid; idx < BB * S2H; idx += NTHR) u2h[idx] = (f16)0.0f;

    const float wfc_r = (lane < HID) ? w_fc[lane] : 0.0f;  // used by waves 4-7
    const float bfc = b_fc[0];
    float c1 = 0.0f, c2 = 0.0f;

    __syncthreads();
    if (wv == 7 && lane < BB) {   // x(t=0)
        const float4 x0 = *reinterpret_cast<const float4*>(x + (size_t)(bbase + lane) * 4);
        f16x2 p0 = {(f16)x0.x, (f16)x0.y}, p1 = {(f16)x0.z, (f16)x0.w};
        uint2 pk;
        pk.x = __builtin_bit_cast(unsigned, p0);
        pk.y = __builtin_bit_cast(unsigned, p1);
        *reinterpret_cast<uint2*>(u1h + lane * S1H) = pk;
    }
    __syncthreads();

#pragma unroll 1
    for (int t = 0; t < SEQ; ++t) {
        // x(t+1) prefetch (wave 7, lanes 0..3)
        float4 xr = make_float4(0.f, 0.f, 0.f, 0.f);
        if (wv == 7 && lane < BB) {
            int tn = (t + 1 < SEQ) ? t + 1 : SEQ - 1;
            xr = *reinterpret_cast<const float4*>(
                x + ((size_t)tn * BATCH + bbase + lane) * 4);
        }

        // ---------------- L1 gates -> G1 ----------------
        {
            uint4 U1r[Q1];
#pragma unroll
            for (int q = 0; q < Q1; ++q) U1r[q] = u1q[b * Q1 + q];
            int rA = r0 + s;                       // 16 rows
            float acc = B1f[rA];
#pragma unroll
            for (int q = 0; q < Q1; ++q) acc = dotq(w1q[rA * Q1 + q], U1r[q], acc);
            G1f[b * NG + rA] = acc;
            if (s < 9) {                           // remaining 9 rows
                int rB = r0 + 16 + s;
                float a2 = B1f[rB];
#pragma unroll
                for (int q = 0; q < Q1; ++q) a2 = dotq(w1q[rB * Q1 + q], U1r[q], a2);
                G1f[b * NG + rB] = a2;
            }
        }
        __syncthreads();  // bar A

        // ---------------- L1 update (waves 0-3) + x(t+1) store (wave 7) ----
        if (wv < 4) {
            if (lane < HID) {
                float gi = G1f[ubat * NG + lane];
                float gf = G1f[ubat * NG + HID + lane];
                float gg = G1f[ubat * NG + 2 * HID + lane];
                float go = G1f[ubat * NG + 3 * HID + lane];
                float ig = sigf(gi), fg = sigf(gf), cg = tanhf_(gg), og = sigf(go);
                c1 = fg * c1 + ig * cg;
                float h1 = og * tanhf_(c1);
                u1h[ubat * S1H + 4 + lane] = (f16)h1;
                u2h[ubat * S2H + lane] = (f16)fmaxf(h1, 0.0f);
            }
        } else if (wv == 7 && lane < BB) {
            f16x2 p0 = {(f16)xr.x, (f16)xr.y}, p1 = {(f16)xr.z, (f16)xr.w};
            uint2 pk;
            pk.x = __builtin_bit_cast(unsigned, p0);
            pk.y = __builtin_bit_cast(unsigned, p1);
            *reinterpret_cast<uint2*>(u1h + lane * S1H) = pk;
        }
        __syncthreads();  // bar B

        // ---------------- L2 gates -> G2 ----------------
        {
            uint4 U2r[Q2];
#pragma unroll
            for (int q = 0; q < Q2; ++q) U2r[q] = u2q[b * Q2 + q];
            int rA = r0 + s;
            float acc = B2f[rA];
#pragma unroll
            for (int q = 0; q < Q2; ++q) acc = dotq(w2q[rA * Q2 + q], U2r[q], acc);
            G2f[b * NG + rA] = acc;
            if (s < 9) {
                int rB = r0 + 16 + s;
                float a2 = B2f[rB];
#pragma unroll
                for (int q = 0; q < Q2; ++q) a2 = dotq(w2q[rB * Q2 + q], U2r[q], a2);
                G2f[b * NG + rB] = a2;
            }
        }
        __syncthreads();  // bar C

        // ------- L2 update (waves 4-7) + in-wave fc reduce; NO bar D -------
        // Safe: next iteration's L1 gates touch only G1/u1h/w1, disjoint from
        // G2 reads and u2h[h2]/out writes here; u2h[h2] is next read at L2
        // gates(t+1), which is behind bars A+B of t+1.
        if (wv >= 4) {
            float p = 0.0f;
            if (lane < HID) {
                float gi = G2f[ubat * NG + lane];
                float gf = G2f[ubat * NG + HID + lane];
                float gg = G2f[ubat * NG + 2 * HID + lane];
                float go = G2f[ubat * NG + 3 * HID + lane];
                float ig = sigf(gi), fg = sigf(gf), cg = tanhf_(gg), og = sigf(go);
                c2 = fg * c2 + ig * cg;
                float h2 = og * tanhf_(c2);
                u2h[ubat * S2H + HID + lane] = (f16)h2;
                p = fmaxf(h2, 0.0f) * wfc_r;
            }
            p += __shfl_xor(p, 1);  p += __shfl_xor(p, 2);
            p += __shfl_xor(p, 4);  p += __shfl_xor(p, 8);
            p += __shfl_xor(p, 16); p += __shfl_xor(p, 32);
            if (lane == 0) out[(size_t)t * BATCH + bbase + ubat] = p + bfc;
        }
    }
}

extern "C" void kernel_launch(void* const* d_in, const int* in_sizes, int n_in,
                              void* d_out, int out_size, void* d_ws, size_t ws_size,
                              hipStream_t stream) {
    const float* X    = (const float*)d_in[0];
    const float* Wih1 = (const float*)d_in[1];
    const float* Whh1 = (const float*)d_in[2];
    const float* Bih1 = (const float*)d_in[3];
    const float* Bhh1 = (const float*)d_in[4];
    const float* Wih2 = (const float*)d_in[5];
    const float* Whh2 = (const float*)d_in[6];
    const float* Bih2 = (const float*)d_in[7];
    const float* Bhh2 = (const float*)d_in[8];
    const float* Wfc  = (const float*)d_in[9];
    const float* Bfc  = (const float*)d_in[10];
    float* out = (float*)d_out;

    (void)hipFuncSetAttribute((const void*)lstm2_fused,
                              hipFuncAttributeMaxDynamicSharedMemorySize,
                              (int)LDS_BYTES);

    lstm2_fused<<<dim3(NBLK), dim3(NTHR), LDS_BYTES, stream>>>(
        X, Wih1, Whh1, Bih1, Bhh1, Wih2, Whh2, Bih2, Bhh2, Wfc, Bfc, out);
}

// Round 4
// 735.974 us; speedup vs baseline: 2.9999x; 2.1032x over previous
//
#include <hip/hip_runtime.h>
#include <cstdint>

#define SEQ 512
#define BATCH 2048
#define HID 50
#define NG 200            // 4*H
#define BB 8              // real batches per block (M padded to 16)
#define NTHR 512          // 8 waves
#define NBLK (BATCH / BB) // 256 blocks -> 1 per CU
#define NT 13             // N-tiles of 16 (200 -> 208)
#define S1H 72            // u1 row stride in halves: [x(4)|h1(50)|zero..64|unused..72], 144 B
#define S2H 136           // u2 row stride: [relu(h1)(50)|h2(50)|zero..128|unused..136], 272 B
#define NGP 212           // G row stride in floats (2-way banks only)

typedef _Float16 f16;
typedef _Float16 v8h  __attribute__((ext_vector_type(8)));
typedef float    v4f  __attribute__((ext_vector_type(4)));

__device__ __forceinline__ float sigf(float x) {
    return __builtin_amdgcn_rcpf(1.0f + __expf(-x));
}
__device__ __forceinline__ float tanhf_(float x) {
    return 1.0f - 2.0f * __builtin_amdgcn_rcpf(1.0f + __expf(2.0f * x));
}

__global__ __launch_bounds__(NTHR, 2) void lstm2_fused(
    const float* __restrict__ x,
    const float* __restrict__ w_ih1, const float* __restrict__ w_hh1,
    const float* __restrict__ b_ih1, const float* __restrict__ b_hh1,
    const float* __restrict__ w_ih2, const float* __restrict__ w_hh2,
    const float* __restrict__ b_ih2, const float* __restrict__ b_hh2,
    const float* __restrict__ w_fc, const float* __restrict__ b_fc,
    float* __restrict__ out)
{
    __shared__ __align__(16) f16  u1h[16 * S1H];
    __shared__ __align__(16) f16  u2h[16 * S2H];
    __shared__ __align__(16) float G1f[16 * NGP];
    __shared__ __align__(16) float G2f[16 * NGP];
    __shared__ float B1s[NG], B2s[NG];

    const int tid  = threadIdx.x;
    const int wv   = tid >> 6;
    const int lane = tid & 63;
    const int m    = lane & 15;     // MFMA m / n position
    const int q    = lane >> 4;     // quad 0..3
    const int bbase = blockIdx.x * BB;

    // ---- weight-stationary B fragments in VGPRs: wave owns N-tiles {wv, wv+8} ----
    // B-frag element j: row r = nt*16 + (lane&15), k = kt*32 + q*8 + j  (m92 B^T pattern)
    v8h W1f[2][2];   // [tile][ktile]  L1: K=54 -> 2 ktiles
    v8h W2f[2][4];   // L2: K=100 -> 4 ktiles
    {
        const int nts[2] = {wv, wv + 8};
#pragma unroll
        for (int i = 0; i < 2; ++i) {
            int r = nts[i] * 16 + m;
            bool rv = (nts[i] < NT) && (r < NG);
#pragma unroll
            for (int kt = 0; kt < 2; ++kt) {
                v8h f;
#pragma unroll
                for (int j = 0; j < 8; ++j) {
                    int k = kt * 32 + q * 8 + j;
                    float v = 0.0f;
                    if (rv) {
                        if (k < 4) v = w_ih1[r * 4 + k];
                        else if (k < 54) v = w_hh1[r * HID + (k - 4)];
                    }
                    f[j] = (f16)v;
                }
                W1f[i][kt] = f;
            }
#pragma unroll
            for (int kt = 0; kt < 4; ++kt) {
                v8h f;
#pragma unroll
                for (int j = 0; j < 8; ++j) {
                    int k = kt * 32 + q * 8 + j;
                    float v = 0.0f;
                    if (rv) {
                        if (k < HID) v = w_ih2[r * HID + k];
                        else if (k < 2 * HID) v = w_hh2[r * HID + (k - HID)];
                    }
                    f[j] = (f16)v;
                }
                W2f[i][kt] = f;
            }
        }
    }

    // ---- LDS init ----
    for (int i = tid; i < 16 * S1H; i += NTHR) u1h[i] = (f16)0.0f;
    for (int i = tid; i < 16 * S2H; i += NTHR) u2h[i] = (f16)0.0f;
    if (tid < NG) {
        B1s[tid] = b_ih1[tid] + b_hh1[tid];
        B2s[tid] = b_ih2[tid] + b_hh2[tid];
    }
    const float wfc_r = (lane < HID) ? w_fc[lane] : 0.0f;
    const float bfc = b_fc[0];
    float c1 = 0.0f, c2 = 0.0f;

    __syncthreads();
    if (lane == 50) {   // x(0): wave wv owns batch wv
        const float4 x0 = *reinterpret_cast<const float4*>(x + (size_t)(bbase + wv) * 4);
        f16 p[4] = {(f16)x0.x, (f16)x0.y, (f16)x0.z, (f16)x0.w};
        *reinterpret_cast<uint2*>(&u1h[wv * S1H]) = *reinterpret_cast<uint2*>(p);
    }
    __syncthreads();

#pragma unroll 1
    for (int t = 0; t < SEQ; ++t) {
        // x(t+1) prefetch: wave wv, lane 50 loads batch wv
        float4 xr;
        if (lane == 50) {
            int tn = (t + 1 < SEQ) ? t + 1 : SEQ - 1;
            xr = *reinterpret_cast<const float4*>(
                x + ((size_t)tn * BATCH + bbase + wv) * 4);
        }

        // ---------------- L1 gates (MFMA) -> G1 ----------------
        {
            v8h a0 = *reinterpret_cast<const v8h*>(&u1h[m * S1H + q * 8]);
            v8h a1 = *reinterpret_cast<const v8h*>(&u1h[m * S1H + 32 + q * 8]);
            v4f acc = {0.f, 0.f, 0.f, 0.f};
            acc = __builtin_amdgcn_mfma_f32_16x16x32_f16(a0, W1f[0][0], acc, 0, 0, 0);
            acc = __builtin_amdgcn_mfma_f32_16x16x32_f16(a1, W1f[0][1], acc, 0, 0, 0);
            int c0 = wv * 16 + m;
#pragma unroll
            for (int rg = 0; rg < 4; ++rg) G1f[(q * 4 + rg) * NGP + c0] = acc[rg];
            if (wv < 5) {
                v4f a2 = {0.f, 0.f, 0.f, 0.f};
                a2 = __builtin_amdgcn_mfma_f32_16x16x32_f16(a0, W1f[1][0], a2, 0, 0, 0);
                a2 = __builtin_amdgcn_mfma_f32_16x16x32_f16(a1, W1f[1][1], a2, 0, 0, 0);
                int c1c = (wv + 8) * 16 + m;
#pragma unroll
                for (int rg = 0; rg < 4; ++rg) G1f[(q * 4 + rg) * NGP + c1c] = a2[rg];
            }
        }
        __syncthreads();  // bar A

        // ---------------- L1 update: wave wv = batch wv, lane = unit ----------------
        if (lane < HID) {
            float gi = G1f[wv * NGP + lane]           + B1s[lane];
            float gf = G1f[wv * NGP + HID + lane]     + B1s[HID + lane];
            float gg = G1f[wv * NGP + 2 * HID + lane] + B1s[2 * HID + lane];
            float go = G1f[wv * NGP + 3 * HID + lane] + B1s[3 * HID + lane];
            float ig = sigf(gi), fg = sigf(gf), cg = tanhf_(gg), og = sigf(go);
            c1 = fg * c1 + ig * cg;
            float h1 = og * tanhf_(c1);
            u1h[wv * S1H + 4 + lane] = (f16)h1;
            u2h[wv * S2H + lane] = (f16)fmaxf(h1, 0.0f);
        } else if (lane == 50) {
            f16 p[4] = {(f16)xr.x, (f16)xr.y, (f16)xr.z, (f16)xr.w};
            *reinterpret_cast<uint2*>(&u1h[wv * S1H]) = *reinterpret_cast<uint2*>(p);
        }
        __syncthreads();  // bar B

        // ---------------- L2 gates (MFMA) -> G2 ----------------
        {
            v8h a0 = *reinterpret_cast<const v8h*>(&u2h[m * S2H + q * 8]);
            v8h a1 = *reinterpret_cast<const v8h*>(&u2h[m * S2H + 32 + q * 8]);
            v8h a2 = *reinterpret_cast<const v8h*>(&u2h[m * S2H + 64 + q * 8]);
            v8h a3 = *reinterpret_cast<const v8h*>(&u2h[m * S2H + 96 + q * 8]);
            v4f acc = {0.f, 0.f, 0.f, 0.f};
            acc = __builtin_amdgcn_mfma_f32_16x16x32_f16(a0, W2f[0][0], acc, 0, 0, 0);
            acc = __builtin_amdgcn_mfma_f32_16x16x32_f16(a1, W2f[0][1], acc, 0, 0, 0);
            acc = __builtin_amdgcn_mfma_f32_16x16x32_f16(a2, W2f[0][2], acc, 0, 0, 0);
            acc = __builtin_amdgcn_mfma_f32_16x16x32_f16(a3, W2f[0][3], acc, 0, 0, 0);
            int c0 = wv * 16 + m;
#pragma unroll
            for (int rg = 0; rg < 4; ++rg) G2f[(q * 4 + rg) * NGP + c0] = acc[rg];
            if (wv < 5) {
                v4f ac2 = {0.f, 0.f, 0.f, 0.f};
                ac2 = __builtin_amdgcn_mfma_f32_16x16x32_f16(a0, W2f[1][0], ac2, 0, 0, 0);
                ac2 = __builtin_amdgcn_mfma_f32_16x16x32_f16(a1, W2f[1][1], ac2, 0, 0, 0);
                ac2 = __builtin_amdgcn_mfma_f32_16x16x32_f16(a2, W2f[1][2], ac2, 0, 0, 0);
                ac2 = __builtin_amdgcn_mfma_f32_16x16x32_f16(a3, W2f[1][3], ac2, 0, 0, 0);
                int c1c = (wv + 8) * 16 + m;
#pragma unroll
                for (int rg = 0; rg < 4; ++rg) G2f[(q * 4 + rg) * NGP + c1c] = ac2[rg];
            }
        }
        __syncthreads();  // bar C

        // ------- L2 update + in-wave fc reduce; no bar D (see barrier proof) -------
        // update2(t) reads G2 / writes u2h[h2]; next writer of G2 is gates2(t+1),
        // which every wave reaches only after bars A+B of t+1; next reader of
        // u2h[h2] is gates2(t+1). Program order per wave puts update2(t) before
        // barA(t+1), so both hazards are fenced by barA+barB of t+1.
        {
            float p = 0.0f;
            if (lane < HID) {
                float gi = G2f[wv * NGP + lane]           + B2s[lane];
                float gf = G2f[wv * NGP + HID + lane]     + B2s[HID + lane];
                float gg = G2f[wv * NGP + 2 * HID + lane] + B2s[2 * HID + lane];
                float go = G2f[wv * NGP + 3 * HID + lane] + B2s[3 * HID + lane];
                float ig = sigf(gi), fg = sigf(gf), cg = tanhf_(gg), og = sigf(go);
                c2 = fg * c2 + ig * cg;
                float h2 = og * tanhf_(c2);
                u2h[wv * S2H + HID + lane] = (f16)h2;
                p = fmaxf(h2, 0.0f) * wfc_r;
            }
            p += __shfl_xor(p, 1);  p += __shfl_xor(p, 2);
            p += __shfl_xor(p, 4);  p += __shfl_xor(p, 8);
            p += __shfl_xor(p, 16); p += __shfl_xor(p, 32);
            if (lane == 0) out[(size_t)t * BATCH + bbase + wv] = p + bfc;
        }
    }
}

extern "C" void kernel_launch(void* const* d_in, const int* in_sizes, int n_in,
                              void* d_out, int out_size, void* d_ws, size_t ws_size,
                              hipStream_t stream) {
    const float* X    = (const float*)d_in[0];
    const float* Wih1 = (const float*)d_in[1];
    const float* Whh1 = (const float*)d_in[2];
    const float* Bih1 = (const float*)d_in[3];
    const float* Bhh1 = (const float*)d_in[4];
    const float* Wih2 = (const float*)d_in[5];
    const float* Whh2 = (const float*)d_in[6];
    const float* Bih2 = (const float*)d_in[7];
    const float* Bhh2 = (const float*)d_in[8];
    const float* Wfc  = (const float*)d_in[9];
    const float* Bfc  = (const float*)d_in[10];
    float* out = (float*)d_out;

    lstm2_fused<<<dim3(NBLK), dim3(NTHR), 0, stream>>>(
        X, Wih1, Whh1, Bih1, Bhh1, Wih2, Whh2, Bih2, Bhh2, Wfc, Bfc, out);
}